// Round 2
// baseline (72.750 us; speedup 1.0000x reference)
//
#include <hip/hip_runtime.h>

// SoftPixelCNN: out[v, o*64+f] = (1/K) * sum_k exp(-A*d[o,v,k]) * feats[nidx[v,k], f]
// d[o,v,k] = ||(c_v + off_o) - c_n||^2 = base + 2*delta.off_o + ||off_o||^2, A = 10*length_scale.
// Offsets (meshgrid-xy order): [0, -e1, -e0, -e2, -e3, +e3, +e2, +e0, +e1].
// NUMERICS: must exponentiate the COMBINED exponent (always <= 0); factoring into
// exp(-A*base)*exp(+/-2A*delta_j) produces 0*inf = NaN for far neighbours.

#define KNB 32
#define FDIM 64
#define ODIM 9

__global__ __launch_bounds__(256) void spcnn_kernel(
    const float* __restrict__ coords,   // (V,4)
    const float* __restrict__ feats,    // (V,64)
    const int*   __restrict__ nidx,     // (V,32)
    const float* __restrict__ lscale,   // (1,)
    float* __restrict__ out)            // (V,576)
{
    __shared__ float wlds[4][KNB][12];  // [warp][k][0..8]=weights, [9]=row byte-offset bits
    const int warp = threadIdx.x >> 6;
    const int lane = threadIdx.x & 63;
    const int v = blockIdx.x * 4 + warp;

    const float A = 10.0f * lscale[0];

    // ---- phase 1: lanes 0..31 compute 9 weights + feature-row offset for their k ----
    if (lane < 32) {
        const int k = lane;
        const int idx = nidx[v * KNB + k];
        const float4 cn = *(const float4*)(coords + (size_t)idx * 4);
        const float4 cv = *(const float4*)(coords + (size_t)v * 4);
        const float d0 = cv.x - cn.x, d1 = cv.y - cn.y, d2 = cv.z - cn.z, d3 = cv.w - cn.w;
        const float base = d0*d0 + d1*d1 + d2*d2 + d3*d3;

        const float ex_base = -A * base;          // exponent for origin offset
        const float bmA = ex_base - A;            // ... - A*||off||^2 (==1 for axis offsets)
        const float t0 = 2.0f*A*d0, t1 = 2.0f*A*d1, t2 = 2.0f*A*d2, t3 = 2.0f*A*d3;
        const float s = 1.0f / (float)KNB;        // fold mean-over-K

        // every argument is -A*||delta+off||^2 <= 0 -> exp in (0,1], no overflow
        const float w0 = __expf(ex_base)  * s;
        const float w1 = __expf(bmA + t1) * s;    // o = -e1
        const float w2 = __expf(bmA + t0) * s;    // o = -e0
        const float w3 = __expf(bmA + t2) * s;    // o = -e2
        const float w4 = __expf(bmA + t3) * s;    // o = -e3
        const float w5 = __expf(bmA - t3) * s;    // o = +e3
        const float w6 = __expf(bmA - t2) * s;    // o = +e2
        const float w7 = __expf(bmA - t0) * s;    // o = +e0
        const float w8 = __expf(bmA - t1) * s;    // o = +e1

        float* wp = wlds[warp][k];
        *(float4*)(wp)     = make_float4(w0, w1, w2, w3);
        *(float4*)(wp + 4) = make_float4(w4, w5, w6, w7);
        wp[8] = w8;
        ((unsigned*)wp)[9] = (unsigned)idx * (FDIM * 4); // byte offset of feature row
    }
    __syncthreads();

    // ---- phase 2: lane = feature index f; accumulate 9 outputs over k ----
    const int f = lane;
    float acc0=0.f,acc1=0.f,acc2=0.f,acc3=0.f,acc4=0.f,acc5=0.f,acc6=0.f,acc7=0.f,acc8=0.f;
    const float* wbase = wlds[warp][0];

    #pragma unroll
    for (int k = 0; k < KNB; ++k) {
        const float* wp = wbase + k * 12;
        const float4 wa = *(const float4*)wp;        // broadcast ds_read_b128
        const float4 wb = *(const float4*)(wp + 4);  // broadcast ds_read_b128
        const float2 wc = *(const float2*)(wp + 8);  // broadcast ds_read_b64 (w8 + off)
        unsigned off = __float_as_uint(wc.y);
        off = __builtin_amdgcn_readfirstlane(off);   // SGPR base for the gather
        const float* row = (const float*)((const char*)feats + off);
        const float g = row[f];                       // coalesced 256B row load
        acc0 += wa.x * g; acc1 += wa.y * g; acc2 += wa.z * g; acc3 += wa.w * g;
        acc4 += wb.x * g; acc5 += wb.y * g; acc6 += wb.z * g; acc7 += wb.w * g;
        acc8 += wc.x * g;
    }

    float* op = out + (size_t)v * (ODIM * FDIM) + f;
    op[0*FDIM] = acc0; op[1*FDIM] = acc1; op[2*FDIM] = acc2;
    op[3*FDIM] = acc3; op[4*FDIM] = acc4; op[5*FDIM] = acc5;
    op[6*FDIM] = acc6; op[7*FDIM] = acc7; op[8*FDIM] = acc8;
}

extern "C" void kernel_launch(void* const* d_in, const int* in_sizes, int n_in,
                              void* d_out, int out_size, void* d_ws, size_t ws_size,
                              hipStream_t stream) {
    const float* coords = (const float*)d_in[0];   // (V,4) f32
    const float* feats  = (const float*)d_in[1];   // (V,64) f32
    // d_in[2] = distsq — unused on the inference path
    const int*   nbidx  = (const int*)d_in[3];     // (V,32) i32
    const float* lscale = (const float*)d_in[4];   // (1,) f32

    const int V = in_sizes[0] / 4;                 // 50000
    const int blocks = V / 4;                      // 4 vertices per 256-thread block

    spcnn_kernel<<<blocks, 256, 0, stream>>>(coords, feats, nbidx, lscale, (float*)d_out);
}

// Round 3
// 71.633 us; speedup vs baseline: 1.0156x; 1.0156x over previous
//
#include <hip/hip_runtime.h>

// SoftPixelCNN: out[v, o*64+f] = (1/K) * sum_k exp(-A*d[o,v,k]) * feats[nidx[v,k], f]
// d[o,v,k] = ||(c_v + off_o) - c_n||^2 = base + 2*delta.off_o + ||off_o||^2, A = 10*length_scale.
// Offsets (meshgrid-xy order): [0, -e1, -e0, -e2, -e3, +e3, +e2, +e0, +e1].
// NUMERICS: exponentiate the COMBINED exponent (always <= 0); factoring into
// exp(-A*base)*exp(+/-2A*delta_j) gives 0*inf = NaN for far neighbours.
// STRUCTURE (r3): indices via v_readlane (no LDS/readfirstlane on address path),
// all 32 gathers issued up front into registers -> latency hidden under FMA stream.

#define KNB 32
#define FDIM 64
#define ODIM 9

__global__ __launch_bounds__(256) void spcnn_kernel(
    const float* __restrict__ coords,   // (V,4)
    const float* __restrict__ feats,    // (V,64)
    const int*   __restrict__ nidx,     // (V,32)
    const float* __restrict__ lscale,   // (1,)
    float* __restrict__ out)            // (V,576)
{
    __shared__ float wlds[4][KNB][12];  // [warp][k][0..8] = weights (stride 12 for b128 align)
    const int warp = threadIdx.x >> 6;
    const int lane = threadIdx.x & 63;
    const int v = blockIdx.x * 4 + warp;

    const float A = 10.0f * lscale[0];

    // every lane holds the index for k = lane&31 (two copies per wave)
    const int myidx = nidx[v * KNB + (lane & 31)];

    // ---- phase 1: lanes 0..31 compute the 9 weights for their k ----
    if (lane < 32) {
        const float4 cn = *(const float4*)(coords + (size_t)(unsigned)myidx * 4);
        const float4 cv = *(const float4*)(coords + (size_t)v * 4);
        const float d0 = cv.x - cn.x, d1 = cv.y - cn.y, d2 = cv.z - cn.z, d3 = cv.w - cn.w;
        const float base = d0*d0 + d1*d1 + d2*d2 + d3*d3;

        const float ex_base = -A * base;
        const float bmA = ex_base - A;            // minus A*||off||^2 (=1 for axis offsets)
        const float t0 = 2.0f*A*d0, t1 = 2.0f*A*d1, t2 = 2.0f*A*d2, t3 = 2.0f*A*d3;
        const float s = 1.0f / (float)KNB;        // fold mean-over-K

        const float w0 = __expf(ex_base)  * s;
        const float w1 = __expf(bmA + t1) * s;    // o = -e1
        const float w2 = __expf(bmA + t0) * s;    // o = -e0
        const float w3 = __expf(bmA + t2) * s;    // o = -e2
        const float w4 = __expf(bmA + t3) * s;    // o = -e3
        const float w5 = __expf(bmA - t3) * s;    // o = +e3
        const float w6 = __expf(bmA - t2) * s;    // o = +e2
        const float w7 = __expf(bmA - t0) * s;    // o = +e0
        const float w8 = __expf(bmA - t1) * s;    // o = +e1

        float* wp = wlds[warp][lane];
        *(float4*)(wp)     = make_float4(w0, w1, w2, w3);
        *(float4*)(wp + 4) = make_float4(w4, w5, w6, w7);
        wp[8] = w8;
    }
    __syncthreads();

    // ---- phase 2: lane = feature f. Issue ALL 32 gathers first (latency hiding). ----
    const int f = lane;
    float g[KNB];
    #pragma unroll
    for (int k = 0; k < KNB; ++k) {
        const unsigned idx = (unsigned)__builtin_amdgcn_readlane(myidx, k); // SGPR
        g[k] = feats[(size_t)idx * FDIM + f];    // SGPR base + coalesced 256B row
    }

    float acc0=0.f,acc1=0.f,acc2=0.f,acc3=0.f,acc4=0.f,acc5=0.f,acc6=0.f,acc7=0.f,acc8=0.f;
    const float* wbase = wlds[warp][0];
    #pragma unroll
    for (int k = 0; k < KNB; ++k) {
        const float* wp = wbase + k * 12;
        const float4 wa = *(const float4*)wp;        // broadcast ds_read_b128
        const float4 wb = *(const float4*)(wp + 4);  // broadcast ds_read_b128
        const float w8 = wp[8];                      // broadcast ds_read_b32
        const float gk = g[k];
        acc0 += wa.x * gk; acc1 += wa.y * gk; acc2 += wa.z * gk; acc3 += wa.w * gk;
        acc4 += wb.x * gk; acc5 += wb.y * gk; acc6 += wb.z * gk; acc7 += wb.w * gk;
        acc8 += w8 * gk;
    }

    float* op = out + (size_t)v * (ODIM * FDIM) + f;
    op[0*FDIM] = acc0; op[1*FDIM] = acc1; op[2*FDIM] = acc2;
    op[3*FDIM] = acc3; op[4*FDIM] = acc4; op[5*FDIM] = acc5;
    op[6*FDIM] = acc6; op[7*FDIM] = acc7; op[8*FDIM] = acc8;
}

extern "C" void kernel_launch(void* const* d_in, const int* in_sizes, int n_in,
                              void* d_out, int out_size, void* d_ws, size_t ws_size,
                              hipStream_t stream) {
    const float* coords = (const float*)d_in[0];   // (V,4) f32
    const float* feats  = (const float*)d_in[1];   // (V,64) f32
    // d_in[2] = distsq — unused on the inference path
    const int*   nbidx  = (const int*)d_in[3];     // (V,32) i32
    const float* lscale = (const float*)d_in[4];   // (1,) f32

    const int V = in_sizes[0] / 4;                 // 50000
    const int blocks = V / 4;                      // 4 vertices per 256-thread block

    spcnn_kernel<<<blocks, 256, 0, stream>>>(coords, feats, nbidx, lscale, (float*)d_out);
}